// Round 6
// baseline (1316.945 us; speedup 1.0000x reference)
//
#include <hip/hip_runtime.h>

// Problem constants (from reference)
constexpr int B_ = 16, T_ = 128, S_ = 128;
constexpr int ROWS = B_ * S_;        // 2048
constexpr int NSTEPS = T_ - 1;       // 127
constexpr int TPRED = 20;
constexpr int TOUT = NSTEPS - TPRED; // 107
constexpr int TB = 512;              // 8 waves
constexpr int NBLK = 160;            // 16 n + 16 s + 128 d blocks

// ws layout in 4-byte units.
constexpr int OFF_HN = 0;                       // hn[4][2048][64] f16 (parity = t&3)
constexpr int OFF_HS = OFF_HN + 262144;
constexpr int OFF_HD = OFF_HS + 262144;         // hd[2][2048][128] f16 (parity = t&1)
constexpr int OFF_BAR = OFF_HD + 262144;        // counters (8192 dw)
constexpr int OFF_OUTS = OFF_BAR + 8192;        // outs[127][2048][2] f32 (atomic-accum)
constexpr int OFF_NPK = OFF_OUTS + NSTEPS * ROWS * 2;
constexpr int NPK_DW = 16 * 7 * 256;            // 28672
constexpr int OFF_SPK = OFF_NPK + NPK_DW;
constexpr int OFF_DPK = OFF_SPK + NPK_DW;       // 32 nt * 16 tiles * 256 dw
constexpr int DPK_DW = 32 * 16 * 256;           // 131072
constexpr int PACK_DWORDS = 2 * NPK_DW + DPK_DW;
constexpr int ZERO_DW = OFF_NPK;                // zero h, counters, outs

typedef _Float16 half8 __attribute__((ext_vector_type(8)));
typedef float float4v __attribute__((ext_vector_type(4)));
typedef unsigned long long ull;

__device__ __forceinline__ float sigm(float x) { return 1.f / (1.f + __expf(-x)); }
__device__ __forceinline__ float tanh_(float x) { return 2.f / (1.f + __expf(-2.f * x)) - 1.f; }
__device__ __forceinline__ unsigned int pack2(float a, float b) {
    union { unsigned int u; _Float16 h[2]; } x;
    x.h[0] = (_Float16)a; x.h[1] = (_Float16)b; return x.u;
}

// device-coherent (cross-XCD) helpers: relaxed agent-scope atomics bypass the
// per-XCD L2 and hit the coherent memory-side cache. No acquire/release fences
// -> no cache maintenance -> LDS-resident weights/state untouched.
__device__ __forceinline__ unsigned ld_dev_u32(const unsigned* p) {
    return __hip_atomic_load(p, __ATOMIC_RELAXED, __HIP_MEMORY_SCOPE_AGENT);
}
__device__ __forceinline__ ull ld_dev_u64(const ull* p) {
    return __hip_atomic_load(p, __ATOMIC_RELAXED, __HIP_MEMORY_SCOPE_AGENT);
}
__device__ __forceinline__ void st_dev_u64(ull* p, ull v) {
    __hip_atomic_store(p, v, __ATOMIC_RELAXED, __HIP_MEMORY_SCOPE_AGENT);
}
__device__ __forceinline__ void st_dev_f16(_Float16* p, _Float16 v) {
    __hip_atomic_store(p, v, __ATOMIC_RELAXED, __HIP_MEMORY_SCOPE_AGENT);
}
__device__ __forceinline__ void at_add_u32(unsigned* p, unsigned v) {
    __hip_atomic_fetch_add(p, v, __ATOMIC_RELAXED, __HIP_MEMORY_SCOPE_AGENT);
}
__device__ __forceinline__ void at_add_f32(float* p, float v) {
    __hip_atomic_fetch_add(p, v, __ATOMIC_RELAXED, __HIP_MEMORY_SCOPE_AGENT);
}

// ---- pack fp32 weights into MFMA B-fragment tiles (fp16), once per call ----
__global__ __launch_bounds__(256) void pack_weights(
    const float* __restrict__ nWx, const float* __restrict__ nWh,
    const float* __restrict__ nWa, const float* __restrict__ nWb, const float* __restrict__ nb,
    const float* __restrict__ sWx, const float* __restrict__ sWh,
    const float* __restrict__ sWa, const float* __restrict__ sWb, const float* __restrict__ sb,
    const float* __restrict__ dWx, const float* __restrict__ dWh,
    const float* __restrict__ dWa, const float* __restrict__ dWb,
    unsigned int* __restrict__ wsu)
{
    int idx = blockIdx.x * 256 + threadIdx.x;
    if (idx >= PACK_DWORDS) return;
    if (idx < 2 * NPK_DW) {
        bool isS = idx >= NPK_DW;
        int dn = isS ? idx - NPK_DW : idx;
        int tile = dn >> 8;
        int e = (dn & 255) * 2;
        int lane = e >> 3, j0 = e & 7;
        int quad = lane >> 4;
        int nt = tile / 7, tt = tile % 7;
        int col = nt * 16 + (lane & 15);
        float v0, v1;
        if (tt < 6) {
            const float* W = isS ? ((tt < 2) ? sWh : (tt < 4) ? sWa : sWb)
                                 : ((tt < 2) ? nWh : (tt < 4) ? nWa : nWb);
            int k = (tt & 1) * 32 + quad * 8 + j0;
            v0 = W[k * 256 + col]; v1 = W[(k + 1) * 256 + col];
        } else {
            int kl = quad * 8 + j0;
            auto xv = [&](int k) -> float {
                if (!isS) { if (k < 3) return nWx[k * 256 + col]; if (k == 3) return nb[col]; return 0.f; }
                else      { if (k == 4) return sWx[col]; if (k == 5) return sb[col]; return 0.f; }
            };
            v0 = xv(kl); v1 = xv(kl + 1);
        }
        wsu[(isS ? OFF_SPK : OFF_NPK) + dn] = pack2(v0, v1);
    } else {
        int dd = idx - 2 * NPK_DW;
        int tile = dd >> 8;
        int e = (dd & 255) * 2;
        int lane = e >> 3, j0 = e & 7;
        int quad = lane >> 4;
        int nt = tile >> 4, tt = tile & 15;
        const float* W = (tt < 4) ? dWx : (tt < 8) ? dWh : (tt < 12) ? dWa : dWb;
        int k = (tt & 3) * 32 + quad * 8 + j0;
        int col = nt * 16 + (lane & 15);
        wsu[OFF_DPK + dd] = pack2(W[k * 512 + col], W[(k + 1) * 512 + col]);
    }
}

// Weight-stationary persistent pipeline, v2:
// Blocks 0-15:  n-cell, FULL batch (128 rows) each -> zero cross-block deps;
//               recurrence entirely in LDS. Publishes hn(t) to L3 (4 parities).
// Blocks 16-31: s-cell, same.
// Blocks 32-159: d-cell (rg = batch, c = 16-col slice). Critical chain is
//               d(e-1)->d(e) only: poll counters (all threads), stage dec+hd
//               from L3, compute, wide-publish hd, signal.
__global__ __launch_bounds__(TB) void pipe_persist(
    const float* __restrict__ input,
    const float* __restrict__ db,
    const float* __restrict__ onW, const float* __restrict__ onb,
    const float* __restrict__ osW, const float* __restrict__ osb,
    float* __restrict__ ws)
{
    const int tid = threadIdx.x;
    const int wave = tid >> 6, lane = tid & 63;
    const int quad = lane >> 4, l15 = lane & 15;
    const int blk = blockIdx.x;

    unsigned* wsu = (unsigned*)ws;
    unsigned* hnU = wsu + OFF_HN;               // parity stride 65536 u32 (4 par)
    unsigned* hsU = wsu + OFF_HS;
    unsigned* hdU = wsu + OFF_HD;               // parity stride 131072 u32 (2 par)
    unsigned* nsc = wsu + OFF_BAR;              // [16] stride 32: ns epoch adds (2/epoch)
    unsigned* dc  = wsu + OFF_BAR + 1024;       // [16] stride 32: d epoch adds (8/epoch)
    float* outs = ws + OFF_OUTS;

    union SMem {
        struct {  // 162368 B
            _Float16 pk[16 * 7 * 512];          // 114688 B
            _Float16 hst[2][130][72];           // 37440 B
            _Float16 xa[128][40];               // 10240 B
        } ns;
        struct {  // 139808 B
            _Float16 wd[4 * 16 * 512];          // 65536 B
            _Float16 dec[128][136];             // 34816 B
            _Float16 hd[130][136];              // 35360 B
            _Float16 hpub[128][16];             // 4096 B
        } d;
    };
    __shared__ __align__(16) SMem sm;

    if (blk < 32) {
        // ================= n / s role: one block = one full batch =================
        const bool isS = (blk >= 16);
        const int rg = blk & 15;
        _Float16* hH = (_Float16*)(isS ? hsU : hnU);
        unsigned* dcp = dc + rg * 32;

        const ull* pkG = (const ull*)(wsu + (isS ? OFF_SPK : OFF_NPK));
        for (int i = tid; i < 14336; i += TB) ((ull*)sm.ns.pk)[i] = pkG[i];
        for (int i = tid; i < 9360; i += TB) ((unsigned*)sm.ns.hst)[i] = 0u;
        for (int i = tid; i < 2560; i += TB) ((unsigned*)sm.ns.xa)[i] = 0u;
        float4v c4[4];
#pragma unroll
        for (int cg = 0; cg < 4; ++cg) c4[cg] = (float4v){0.f, 0.f, 0.f, 0.f};
        __syncthreads();

        for (int e = 0; e < NSTEPS; ++e) {
            const int pinL = (e + 1) & 1, poutL = e & 1;  // LDS parity
            const int poutG = e & 3;                      // L3 parity
            // stage x(e): row = s
            if (tid < 128) {
                const float* xp = input + ((size_t)(rg * T_ + e) * S_ + tid) * 4;
                unsigned* row = (unsigned*)sm.ns.xa + tid * 20;
                row[0] = pack2(xp[0], xp[1]);
                row[1] = pack2(xp[2], 1.f);
                row[2] = pack2(xp[3], 1.f);
            }
            // backpressure only: parity poutG reused from epoch e-4; its readers
            // (d epoch e-3) must be done: dc >= 8*(e-3). All threads poll (uniform).
            if (e >= 4) {
                unsigned tgt = 8u * (unsigned)(e - 3);
                while (ld_dev_u32(dcp) < tgt) __builtin_amdgcn_s_sleep(1);
            }
            __syncthreads();

            // MFMA: wave = rowtile (16 rows); cg-loop over 4 col-tiles
            const _Float16* hb = &sm.ns.hst[pinL][0][0];
            const int ri = wave * 16 + l15;
            half8 ah0 = *(const half8*)(hb + (ri + 1) * 72 + quad * 8);
            half8 ah1 = *(const half8*)(hb + (ri + 1) * 72 + 32 + quad * 8);
            half8 aa0 = *(const half8*)(hb + (ri + 2) * 72 + quad * 8);
            half8 aa1 = *(const half8*)(hb + (ri + 2) * 72 + 32 + quad * 8);
            half8 ab0 = *(const half8*)(hb + (ri) * 72 + quad * 8);
            half8 ab1 = *(const half8*)(hb + (ri) * 72 + 32 + quad * 8);
            half8 ax  = *(const half8*)(&sm.ns.xa[0][0] + ri * 40 + quad * 8);
            _Float16* hLp = &sm.ns.hst[poutL][0][0];
            _Float16* hGp = hH + (size_t)poutG * 131072 + (size_t)rg * 128 * 64;
#pragma unroll
            for (int cg = 0; cg < 4; ++cg) {
                float4v acc[4];
#pragma unroll
                for (int g = 0; g < 4; ++g) acc[g] = (float4v){0.f, 0.f, 0.f, 0.f};
#pragma unroll
                for (int g = 0; g < 4; ++g) {
                    const _Float16* base = sm.ns.pk + (size_t)(4 * g + cg) * 7 * 512 + lane * 8;
                    acc[g] = __builtin_amdgcn_mfma_f32_16x16x32_f16(ah0, *(const half8*)(base),        acc[g], 0, 0, 0);
                    acc[g] = __builtin_amdgcn_mfma_f32_16x16x32_f16(ah1, *(const half8*)(base + 512),  acc[g], 0, 0, 0);
                    acc[g] = __builtin_amdgcn_mfma_f32_16x16x32_f16(aa0, *(const half8*)(base + 1024), acc[g], 0, 0, 0);
                    acc[g] = __builtin_amdgcn_mfma_f32_16x16x32_f16(aa1, *(const half8*)(base + 1536), acc[g], 0, 0, 0);
                    acc[g] = __builtin_amdgcn_mfma_f32_16x16x32_f16(ab0, *(const half8*)(base + 2048), acc[g], 0, 0, 0);
                    acc[g] = __builtin_amdgcn_mfma_f32_16x16x32_f16(ab1, *(const half8*)(base + 2560), acc[g], 0, 0, 0);
                    acc[g] = __builtin_amdgcn_mfma_f32_16x16x32_f16(ax,  *(const half8*)(base + 3072), acc[g], 0, 0, 0);
                }
                const int kcol = cg * 16 + l15;
                float4v cold = c4[cg], cnew;
#pragma unroll
                for (int r = 0; r < 4; ++r) {
                    float c2 = sigm(acc[1][r]) * cold[r] + sigm(acc[0][r]) * tanh_(acc[2][r]);
                    float h2 = sigm(acc[3][r]) * tanh_(c2);
                    cnew[r] = c2;
                    int row = wave * 16 + quad * 4 + r;
                    _Float16 hf = (_Float16)h2;
                    hLp[(row + 1) * 72 + kcol] = hf;
                    st_dev_f16(hGp + (size_t)row * 64 + kcol, hf);
                }
                c4[cg] = cnew;
            }
            asm volatile("s_waitcnt vmcnt(0)" ::: "memory");
            __syncthreads();
            if (tid == 0) at_add_u32(nsc + rg * 32, 1u);
        }
    } else {
        // ================= d role =================
        const int idx = blk - 32;
        const int rg = idx >> 3;                // batch
        const int c = idx & 7;                  // 16-col slice
        const int r0 = rg * 128;
        unsigned* dcp = dc + rg * 32;
        unsigned* nscp = nsc + rg * 32;

        // one-time: weight slice (64 KB) to LDS; zero hd edge rows
        const ull* pdG = (const ull*)(wsu + OFF_DPK);
        for (int i = tid; i < 8192; i += TB) {
            int tile = i >> 7, j = i & 127;
            int g = tile >> 4, tt = tile & 15;
            ((ull*)sm.d.wd)[(g * 16 + tt) * 128 + j] =
                pdG[(size_t)((g * 8 + c) * 16 + tt) * 128 + j];
        }
        if (tid < 68) {
            ((unsigned*)&sm.d.hd[0][0])[tid] = 0u;
            ((unsigned*)&sm.d.hd[129][0])[tid] = 0u;
        }
        const int hcol = c * 16 + l15;
        const float won = onW[hcol], wos = osW[hcol];
        float bg[4];
#pragma unroll
        for (int g = 0; g < 4; ++g) bg[g] = db[g * 128 + hcol];
        float4v creg = (float4v){0.f, 0.f, 0.f, 0.f};
        __syncthreads();

        for (int e = 1; e <= NSTEPS; ++e) {
            const int t = e - 1;
            const int pdec = t & 3;             // hn/hs(t) L3 parity
            const int phdin = e & 1;            // hd(t-1) parity
            const int phdout = t & 1;           // hd(t) parity
            // polls: all threads, same line -> 1 transaction per wave per iter
            if (e >= 2) {
                unsigned tgt = 8u * (unsigned)(e - 1);
                while (ld_dev_u32(dcp) < tgt) __builtin_amdgcn_s_sleep(1);
            }
            {
                unsigned tgt = 2u * (unsigned)e;
                while (ld_dev_u32(nscp) < tgt) __builtin_amdgcn_s_sleep(1);
            }
            // stage hd(t-1) rows 1..128 (8 u64/thread)
            const ull* srcH = (const ull*)(hdU + (size_t)phdin * 131072);
#pragma unroll
            for (int i = tid; i < 4096; i += TB) {
                int row = i >> 5, j = i & 31;
                *((ull*)&sm.d.hd[row + 1][0] + j) = ld_dev_u64(srcH + (size_t)(r0 + row) * 32 + j);
            }
            // stage dec = [hn(t) | hs(t)] (8 u64/thread)
            const ull* srcN = (const ull*)(hnU + (size_t)pdec * 32768);
            const ull* srcS = (const ull*)(hsU + (size_t)pdec * 32768);
#pragma unroll
            for (int i = tid; i < 4096; i += TB) {
                int hf = i >> 11, j2 = i & 2047;
                int row = j2 >> 4, j = j2 & 15;
                *((ull*)&sm.d.dec[row][hf * 64] + j) =
                    ld_dev_u64((hf ? srcS : srcN) + (size_t)(r0 + row) * 16 + j);
            }
            __syncthreads();

            // MFMA: wave -> rows wave*16..+15, 4 gates x own 16 cols
            const int ri = wave * 16 + l15;
            half8 fr[16];
#pragma unroll
            for (int kt = 0; kt < 4; ++kt) {
                fr[kt]      = *(const half8*)(&sm.d.dec[ri][0] + kt * 32 + quad * 8);
                fr[4 + kt]  = *(const half8*)(&sm.d.hd[ri + 1][0] + kt * 32 + quad * 8);
                fr[8 + kt]  = *(const half8*)(&sm.d.hd[ri + 2][0] + kt * 32 + quad * 8);
                fr[12 + kt] = *(const half8*)(&sm.d.hd[ri][0] + kt * 32 + quad * 8);
            }
            float4v acc[4];
#pragma unroll
            for (int g = 0; g < 4; ++g) acc[g] = (float4v){0.f, 0.f, 0.f, 0.f};
#pragma unroll
            for (int g = 0; g < 4; ++g) {
                const _Float16* bw = sm.d.wd + (size_t)(g * 16) * 512 + lane * 8;
#pragma unroll
                for (int kt = 0; kt < 16; ++kt)
                    acc[g] = __builtin_amdgcn_mfma_f32_16x16x32_f16(fr[kt], *(const half8*)(bw + kt * 512), acc[g], 0, 0, 0);
            }
            float4v cold = creg, cnew;
#pragma unroll
            for (int r = 0; r < 4; ++r) {
                float c2 = sigm(acc[1][r] + bg[1]) * cold[r] + sigm(acc[0][r] + bg[0]) * tanh_(acc[2][r] + bg[2]);
                float h2 = sigm(acc[3][r] + bg[3]) * tanh_(c2);
                cnew[r] = c2;
                int row = wave * 16 + quad * 4 + r;
                sm.d.hpub[row][l15] = (_Float16)h2;
                float pon = h2 * won, pos = h2 * wos;
#pragma unroll
                for (int off = 8; off; off >>= 1) {
                    pon += __shfl_down(pon, off, 16);
                    pos += __shfl_down(pos, off, 16);
                }
                if (l15 == 0) {
                    float* o = outs + ((size_t)t * ROWS + (r0 + row)) * 2;
                    at_add_f32(o, pon);
                    at_add_f32(o + 1, pos);
                }
            }
            creg = cnew;
            __syncthreads();   // hpub complete
            // wide publish: 1 u64 per thread (own 16 cols x 128 rows = 4 KB)
            {
                int prow = tid >> 2, jj = tid & 3;
                ull v = *((const ull*)&sm.d.hpub[prow][0] + jj);
                st_dev_u64((ull*)hdU + (size_t)phdout * 65536 + (size_t)(r0 + prow) * 32 + c * 4 + jj, v);
            }
            asm volatile("s_waitcnt vmcnt(0)" ::: "memory");
            __syncthreads();   // all publishes drained
            if (tid == 0) at_add_u32(dcp, 1u);
        }
    }
}

// Assemble data outputs for t in [20,126]; head biases added here.
__global__ __launch_bounds__(256) void assemble_kernel(
    const float* __restrict__ input, const float* __restrict__ ws, float* __restrict__ out,
    const float* __restrict__ onb, const float* __restrict__ osb)
{
    const float* outs = ws + OFF_OUTS;
    int idx = blockIdx.x * 256 + threadIdx.x;  // (b, tt, s)
    if (idx >= B_ * TOUT * S_) return;
    float b_on = onb[0], b_os = osb[0];
    int s = idx & 127;
    int tmp = idx >> 7;
    int tt = tmp % TOUT;
    int b = tmp / TOUT;
    int t = tt + TPRED;
    int row = b * S_ + s;
    float o0 = outs[((size_t)t * ROWS + row) * 2 + 0] + b_on;
    float o1 = outs[((size_t)t * ROWS + row) * 2 + 1] + b_os;
    float inflow = (s == 0) ? input[(((size_t)b * T_ + (t + 1)) * S_ + 0) * 4 + 1]
                            : (outs[((size_t)t * ROWS + row - 1) * 2 + 0] + b_on);
    float numc = input[(((size_t)b * T_ + t) * S_ + s) * 4 + 2] + inflow - o0;
    float spd = (s == 0) ? input[(((size_t)b * T_ + (t + 1)) * S_ + 0) * 4 + 3] : o1;
    float4 v = make_float4(o0, inflow, numc, spd);
    reinterpret_cast<float4*>(out)[idx] = v;
}

extern "C" void kernel_launch(void* const* d_in, const int* in_sizes, int n_in,
                              void* d_out, int out_size, void* d_ws, size_t ws_size,
                              hipStream_t stream) {
    const float* input = (const float*)d_in[0];
    const float* nWx = (const float*)d_in[1];
    const float* nWh = (const float*)d_in[2];
    const float* nWa = (const float*)d_in[3];
    const float* nWb = (const float*)d_in[4];
    const float* nb  = (const float*)d_in[5];
    const float* sWx = (const float*)d_in[6];
    const float* sWh = (const float*)d_in[7];
    const float* sWa = (const float*)d_in[8];
    const float* sWb = (const float*)d_in[9];
    const float* sb  = (const float*)d_in[10];
    const float* dWx = (const float*)d_in[11];
    const float* dWh = (const float*)d_in[12];
    const float* dWa = (const float*)d_in[13];
    const float* dWb = (const float*)d_in[14];
    const float* db  = (const float*)d_in[15];
    const float* onW = (const float*)d_in[16];
    const float* onb = (const float*)d_in[17];
    const float* osW = (const float*)d_in[18];
    const float* osb = (const float*)d_in[19];

    float* ws = (float*)d_ws;

    // zero h buffers (all parities), counters, outs accumulator
    hipMemsetAsync(ws, 0, (size_t)ZERO_DW * 4, stream);

    // pack weights into MFMA B-fragment tiles (once per call)
    pack_weights<<<dim3((PACK_DWORDS + 255) / 256), dim3(256), 0, stream>>>(
        nWx, nWh, nWa, nWb, nb, sWx, sWh, sWa, sWb, sb,
        dWx, dWh, dWa, dWb, (unsigned int*)ws);

    // cooperative launch (co-residency guarantee); sync via counters inside
    void* kargs[] = {
        (void*)&input, (void*)&db, (void*)&onW, (void*)&onb,
        (void*)&osW, (void*)&osb, (void*)&ws
    };
    hipLaunchCooperativeKernel((void*)pipe_persist, dim3(NBLK), dim3(TB),
                               kargs, 0, stream);

    int nout = B_ * TOUT * S_;
    assemble_kernel<<<dim3((nout + 255) / 256), dim3(256), 0, stream>>>(
        input, ws, (float*)d_out, onb, osb);
}

// Round 8
// 1185.808 us; speedup vs baseline: 1.1106x; 1.1106x over previous
//
#include <hip/hip_runtime.h>

// Problem constants (from reference)
constexpr int B_ = 16, T_ = 128, S_ = 128;
constexpr int ROWS = B_ * S_;        // 2048
constexpr int NSTEPS = T_ - 1;       // 127
constexpr int TPRED = 20;
constexpr int TOUT = NSTEPS - TPRED; // 107
constexpr int TB = 512;              // 8 waves
constexpr int NBLK = 160;            // 16 n + 16 s + 128 d blocks

// ws layout in 4-byte units.
constexpr int OFF_HN = 0;                       // hn[4][2048][64] f16 (parity = t&3)
constexpr int OFF_HS = OFF_HN + 262144;
constexpr int OFF_HD = OFF_HS + 262144;         // hd[2][2048][128] f16 (parity = t&1)
constexpr int OFF_BAR = OFF_HD + 262144;        // counters (8192 dw)
constexpr int OFF_OUTS = OFF_BAR + 8192;        // outs[127][2048][2] f32 (atomic-accum)
constexpr int OFF_NPK = OFF_OUTS + NSTEPS * ROWS * 2;
constexpr int NPK_DW = 16 * 7 * 256;            // 28672
constexpr int OFF_SPK = OFF_NPK + NPK_DW;
constexpr int OFF_DPK = OFF_SPK + NPK_DW;       // 32 nt * 16 tiles * 256 dw
constexpr int DPK_DW = 32 * 16 * 256;           // 131072
constexpr int PACK_DWORDS = 2 * NPK_DW + DPK_DW;
constexpr int ZERO_DW = OFF_NPK;                // zero h, counters, outs

typedef _Float16 half8 __attribute__((ext_vector_type(8)));
typedef float float4v __attribute__((ext_vector_type(4)));
typedef unsigned long long ull;

__device__ __forceinline__ float sigm(float x) { return 1.f / (1.f + __expf(-x)); }
__device__ __forceinline__ float tanh_(float x) { return 2.f / (1.f + __expf(-2.f * x)) - 1.f; }
__device__ __forceinline__ unsigned int pack2(float a, float b) {
    union { unsigned int u; _Float16 h[2]; } x;
    x.h[0] = (_Float16)a; x.h[1] = (_Float16)b; return x.u;
}

// device-coherent (cross-XCD) helpers: relaxed agent-scope atomics bypass the
// per-XCD L2 and hit the coherent memory-side cache. No acquire/release fences
// -> no cache maintenance. Compiler-tracked (safe waitcnt insertion).
__device__ __forceinline__ unsigned ld_dev_u32(const unsigned* p) {
    return __hip_atomic_load(p, __ATOMIC_RELAXED, __HIP_MEMORY_SCOPE_AGENT);
}
__device__ __forceinline__ ull ld_dev_u64(const ull* p) {
    return __hip_atomic_load(p, __ATOMIC_RELAXED, __HIP_MEMORY_SCOPE_AGENT);
}
__device__ __forceinline__ void st_dev_u64(ull* p, ull v) {
    __hip_atomic_store(p, v, __ATOMIC_RELAXED, __HIP_MEMORY_SCOPE_AGENT);
}
__device__ __forceinline__ void at_add_u32(unsigned* p, unsigned v) {
    __hip_atomic_fetch_add(p, v, __ATOMIC_RELAXED, __HIP_MEMORY_SCOPE_AGENT);
}
__device__ __forceinline__ void at_add_f32(float* p, float v) {
    __hip_atomic_fetch_add(p, v, __ATOMIC_RELAXED, __HIP_MEMORY_SCOPE_AGENT);
}
#define WAIT_VM0() asm volatile("s_waitcnt vmcnt(0)" ::: "memory")

// ---- pack fp32 weights into MFMA B-fragment tiles (fp16), once per call ----
__global__ __launch_bounds__(256) void pack_weights(
    const float* __restrict__ nWx, const float* __restrict__ nWh,
    const float* __restrict__ nWa, const float* __restrict__ nWb, const float* __restrict__ nb,
    const float* __restrict__ sWx, const float* __restrict__ sWh,
    const float* __restrict__ sWa, const float* __restrict__ sWb, const float* __restrict__ sb,
    const float* __restrict__ dWx, const float* __restrict__ dWh,
    const float* __restrict__ dWa, const float* __restrict__ dWb,
    unsigned int* __restrict__ wsu)
{
    int idx = blockIdx.x * 256 + threadIdx.x;
    if (idx >= PACK_DWORDS) return;
    if (idx < 2 * NPK_DW) {
        bool isS = idx >= NPK_DW;
        int dn = isS ? idx - NPK_DW : idx;
        int tile = dn >> 8;
        int e = (dn & 255) * 2;
        int lane = e >> 3, j0 = e & 7;
        int quad = lane >> 4;
        int nt = tile / 7, tt = tile % 7;
        int col = nt * 16 + (lane & 15);
        float v0, v1;
        if (tt < 6) {
            const float* W = isS ? ((tt < 2) ? sWh : (tt < 4) ? sWa : sWb)
                                 : ((tt < 2) ? nWh : (tt < 4) ? nWa : nWb);
            int k = (tt & 1) * 32 + quad * 8 + j0;
            v0 = W[k * 256 + col]; v1 = W[(k + 1) * 256 + col];
        } else {
            int kl = quad * 8 + j0;
            auto xv = [&](int k) -> float {
                if (!isS) { if (k < 3) return nWx[k * 256 + col]; if (k == 3) return nb[col]; return 0.f; }
                else      { if (k == 4) return sWx[col]; if (k == 5) return sb[col]; return 0.f; }
            };
            v0 = xv(kl); v1 = xv(kl + 1);
        }
        wsu[(isS ? OFF_SPK : OFF_NPK) + dn] = pack2(v0, v1);
    } else {
        int dd = idx - 2 * NPK_DW;
        int tile = dd >> 8;
        int e = (dd & 255) * 2;
        int lane = e >> 3, j0 = e & 7;
        int quad = lane >> 4;
        int nt = tile >> 4, tt = tile & 15;
        const float* W = (tt < 4) ? dWx : (tt < 8) ? dWh : (tt < 12) ? dWa : dWb;
        int k = (tt & 3) * 32 + quad * 8 + j0;
        int col = nt * 16 + (lane & 15);
        wsu[OFF_DPK + dd] = pack2(W[k * 512 + col], W[(k + 1) * 512 + col]);
    }
}

// Weight-stationary persistent pipeline, v4:
// Blocks 0-15:  n-cell, full batch (128 rows) -> zero cross-block deps.
// Blocks 16-31: s-cell, same.
// Blocks 32-159: d-cell (rg = batch, c = 16-col slice). Chain: poll -> BATCHED
//   two-phase staging (issue all atomic loads -> write LDS) -> MFMA ->
//   LDS-bounce publish -> vmcnt drain -> signal.
__global__ __launch_bounds__(TB) void pipe_persist(
    const float* __restrict__ input,
    const float* __restrict__ db,
    const float* __restrict__ onW, const float* __restrict__ onb,
    const float* __restrict__ osW, const float* __restrict__ osb,
    float* __restrict__ ws)
{
    const int tid = threadIdx.x;
    const int wave = tid >> 6, lane = tid & 63;
    const int quad = lane >> 4, l15 = lane & 15;
    const int blk = blockIdx.x;

    unsigned* wsu = (unsigned*)ws;
    char* hnB = (char*)(wsu + OFF_HN);          // parity stride 262144 B (4 par)
    char* hsB = (char*)(wsu + OFF_HS);
    char* hdB = (char*)(wsu + OFF_HD);          // parity stride 524288 B (2 par)
    unsigned* nsc = wsu + OFF_BAR;              // [16] stride 32: ns epoch adds (2/epoch)
    unsigned* dc  = wsu + OFF_BAR + 1024;       // [16] stride 32: d epoch adds (8/epoch)
    float* outs = ws + OFF_OUTS;

    union SMem {
        struct {  // 162368 B
            _Float16 pk[16 * 7 * 512];          // 114688 B
            _Float16 hst[2][130][72];           // 37440 B
            _Float16 xa[128][40];               // 10240 B
        } ns;
        struct {  // 139808 B
            _Float16 wd[4 * 16 * 512];          // 65536 B
            _Float16 dec[128][136];             // 34816 B
            _Float16 hd[130][136];              // 35360 B
            _Float16 hpub[128][16];             // 4096 B
        } d;
    };
    __shared__ __align__(16) SMem sm;

    if (blk < 32) {
        // ================= n / s role: one block = one full batch =================
        const bool isS = (blk >= 16);
        const int rg = blk & 15;
        char* hB = isS ? hsB : hnB;
        unsigned* dcp = dc + rg * 32;
        unsigned* nscp = nsc + rg * 32;

        const ull* pkG = (const ull*)(wsu + (isS ? OFF_SPK : OFF_NPK));
        for (int i = tid; i < 14336; i += TB) ((ull*)sm.ns.pk)[i] = pkG[i];
        for (int i = tid; i < 9360; i += TB) ((unsigned*)sm.ns.hst)[i] = 0u;
        for (int i = tid; i < 2560; i += TB) ((unsigned*)sm.ns.xa)[i] = 0u;
        float4v c4[4];
#pragma unroll
        for (int cg = 0; cg < 4; ++cg) c4[cg] = (float4v){0.f, 0.f, 0.f, 0.f};
        __syncthreads();

        for (int e = 0; e < NSTEPS; ++e) {
            const int pinL = (e + 1) & 1, poutL = e & 1;  // LDS parity
            const int poutG = e & 3;                      // L3 parity
            // stage x(e): row = s (plain cached loads; input is immutable)
            if (tid < 128) {
                const float* xp = input + ((size_t)(rg * T_ + e) * S_ + tid) * 4;
                unsigned* row = (unsigned*)sm.ns.xa + tid * 20;
                row[0] = pack2(xp[0], xp[1]);
                row[1] = pack2(xp[2], 1.f);
                row[2] = pack2(xp[3], 1.f);
            }
            // backpressure: parity poutG reused from epoch e-4; its readers
            // (d epoch e-3) must be done.
            if (e >= 4) {
                unsigned tgt = 8u * (unsigned)(e - 3);
                while (ld_dev_u32(dcp) < tgt) __builtin_amdgcn_s_sleep(1);
            }
            __syncthreads();

            // MFMA: wave = rowtile (16 rows); cg-loop over 4 col-tiles
            const _Float16* hb = &sm.ns.hst[pinL][0][0];
            const int ri = wave * 16 + l15;
            half8 ah0 = *(const half8*)(hb + (ri + 1) * 72 + quad * 8);
            half8 ah1 = *(const half8*)(hb + (ri + 1) * 72 + 32 + quad * 8);
            half8 aa0 = *(const half8*)(hb + (ri + 2) * 72 + quad * 8);
            half8 aa1 = *(const half8*)(hb + (ri + 2) * 72 + 32 + quad * 8);
            half8 ab0 = *(const half8*)(hb + (ri) * 72 + quad * 8);
            half8 ab1 = *(const half8*)(hb + (ri) * 72 + 32 + quad * 8);
            half8 ax  = *(const half8*)(&sm.ns.xa[0][0] + ri * 40 + quad * 8);
            _Float16* hLp = &sm.ns.hst[poutL][0][0];
#pragma unroll
            for (int cg = 0; cg < 4; ++cg) {
                float4v acc[4];
#pragma unroll
                for (int g = 0; g < 4; ++g) acc[g] = (float4v){0.f, 0.f, 0.f, 0.f};
#pragma unroll
                for (int g = 0; g < 4; ++g) {
                    const _Float16* base = sm.ns.pk + (size_t)(4 * g + cg) * 7 * 512 + lane * 8;
                    acc[g] = __builtin_amdgcn_mfma_f32_16x16x32_f16(ah0, *(const half8*)(base),        acc[g], 0, 0, 0);
                    acc[g] = __builtin_amdgcn_mfma_f32_16x16x32_f16(ah1, *(const half8*)(base + 512),  acc[g], 0, 0, 0);
                    acc[g] = __builtin_amdgcn_mfma_f32_16x16x32_f16(aa0, *(const half8*)(base + 1024), acc[g], 0, 0, 0);
                    acc[g] = __builtin_amdgcn_mfma_f32_16x16x32_f16(aa1, *(const half8*)(base + 1536), acc[g], 0, 0, 0);
                    acc[g] = __builtin_amdgcn_mfma_f32_16x16x32_f16(ab0, *(const half8*)(base + 2048), acc[g], 0, 0, 0);
                    acc[g] = __builtin_amdgcn_mfma_f32_16x16x32_f16(ab1, *(const half8*)(base + 2560), acc[g], 0, 0, 0);
                    acc[g] = __builtin_amdgcn_mfma_f32_16x16x32_f16(ax,  *(const half8*)(base + 3072), acc[g], 0, 0, 0);
                }
                const int kcol = cg * 16 + l15;
                float4v cold = c4[cg], cnew;
#pragma unroll
                for (int r = 0; r < 4; ++r) {
                    float c2 = sigm(acc[1][r]) * cold[r] + sigm(acc[0][r]) * tanh_(acc[2][r]);
                    float h2 = sigm(acc[3][r]) * tanh_(c2);
                    cnew[r] = c2;
                    int row = wave * 16 + quad * 4 + r;
                    hLp[(row + 1) * 72 + kcol] = (_Float16)h2;
                }
                c4[cg] = cnew;
            }
            __syncthreads();   // hLp complete
            // wide publish via LDS bounce: 4 u64 per thread (128 rows x 128 B)
            {
                char* dst0 = hB + (size_t)poutG * 262144 + (size_t)rg * 16384;
#pragma unroll
                for (int k = 0; k < 4; ++k) {
                    int i = tid + k * 512;       // 0..2047
                    int row = i >> 4, j = i & 15;
                    ull v = *((const ull*)&sm.ns.hst[poutL][row + 1][0] + j);
                    st_dev_u64((ull*)(dst0 + (size_t)row * 128 + (size_t)j * 8), v);
                }
            }
            WAIT_VM0();
            __syncthreads();   // all publishes drained
            if (tid == 0) at_add_u32(nscp, 1u);
        }
    } else {
        // ================= d role =================
        const int idx = blk - 32;
        const int rg = idx >> 3;                // batch
        const int c = idx & 7;                  // 16-col slice
        const int r0 = rg * 128;
        unsigned* dcp = dc + rg * 32;
        unsigned* nscp = nsc + rg * 32;

        // one-time: weight slice (64 KB) to LDS; zero hd edge rows
        const ull* pdG = (const ull*)(wsu + OFF_DPK);
        for (int i = tid; i < 8192; i += TB) {
            int tile = i >> 7, j = i & 127;
            int g = tile >> 4, tt = tile & 15;
            ((ull*)sm.d.wd)[(g * 16 + tt) * 128 + j] =
                pdG[(size_t)((g * 8 + c) * 16 + tt) * 128 + j];
        }
        if (tid < 68) {
            ((unsigned*)&sm.d.hd[0][0])[tid] = 0u;
            ((unsigned*)&sm.d.hd[129][0])[tid] = 0u;
        }
        const int hcol = c * 16 + l15;
        const float won = onW[hcol], wos = osW[hcol];
        float bg[4];
#pragma unroll
        for (int g = 0; g < 4; ++g) bg[g] = db[g * 128 + hcol];
        float4v creg = (float4v){0.f, 0.f, 0.f, 0.f};
        __syncthreads();

        for (int e = 1; e <= NSTEPS; ++e) {
            const int t = e - 1;
            const int pdec = t & 3;             // hn/hs(t) L3 parity
            const int phdin = e & 1;            // hd(t-1) parity
            const int phdout = t & 1;           // hd(t) parity
            // wait ns done epoch t (dec typically ready; ns runs ~3 ahead)
            {
                unsigned tgt = 2u * (unsigned)e;
                while (ld_dev_u32(nscp) < tgt) __builtin_amdgcn_s_sleep(1);
            }
            // stage dec = [hn(t) | hs(t)]: two-phase (issue 8 loads -> write LDS)
            {
                ull t8[8];
#pragma unroll
                for (int k = 0; k < 8; ++k) {
                    int i = tid + k * 512;       // 0..4095
                    int row = i >> 5, j = i & 31;
                    const char* src = (j < 16 ? hnB : hsB) + (size_t)pdec * 262144
                                      + (size_t)(r0 + row) * 128 + (size_t)(j & 15) * 8;
                    t8[k] = ld_dev_u64((const ull*)src);
                }
#pragma unroll
                for (int k = 0; k < 8; ++k) {
                    int i = tid + k * 512;
                    int row = i >> 5, j = i & 31;
                    *((ull*)&sm.d.dec[row][0] + j) = t8[k];
                }
            }
            // wait siblings done epoch e-1 (hd(t-1) published)
            if (e >= 2) {
                unsigned tgt = 8u * (unsigned)(e - 1);
                while (ld_dev_u32(dcp) < tgt) __builtin_amdgcn_s_sleep(1);
            }
            // stage hd(t-1): two-phase (issue 8 loads -> write LDS)
            {
                ull t8[8];
#pragma unroll
                for (int k = 0; k < 8; ++k) {
                    int i = tid + k * 512;
                    int row = i >> 5, j = i & 31;
                    t8[k] = ld_dev_u64((const ull*)(hdB + (size_t)phdin * 524288
                                       + (size_t)(r0 + row) * 256 + (size_t)j * 8));
                }
#pragma unroll
                for (int k = 0; k < 8; ++k) {
                    int i = tid + k * 512;
                    int row = i >> 5, j = i & 31;
                    *((ull*)&sm.d.hd[row + 1][0] + j) = t8[k];
                }
            }
            __syncthreads();

            // MFMA: wave -> rows wave*16..+15, 4 gates x own 16 cols
            const int ri = wave * 16 + l15;
            half8 fr[16];
#pragma unroll
            for (int kt = 0; kt < 4; ++kt) {
                fr[kt]      = *(const half8*)(&sm.d.dec[ri][0] + kt * 32 + quad * 8);
                fr[4 + kt]  = *(const half8*)(&sm.d.hd[ri + 1][0] + kt * 32 + quad * 8);
                fr[8 + kt]  = *(const half8*)(&sm.d.hd[ri + 2][0] + kt * 32 + quad * 8);
                fr[12 + kt] = *(const half8*)(&sm.d.hd[ri][0] + kt * 32 + quad * 8);
            }
            float4v acc[4];
#pragma unroll
            for (int g = 0; g < 4; ++g) acc[g] = (float4v){0.f, 0.f, 0.f, 0.f};
#pragma unroll
            for (int g = 0; g < 4; ++g) {
                const _Float16* bw = sm.d.wd + (size_t)(g * 16) * 512 + lane * 8;
#pragma unroll
                for (int kt = 0; kt < 16; ++kt)
                    acc[g] = __builtin_amdgcn_mfma_f32_16x16x32_f16(fr[kt], *(const half8*)(bw + kt * 512), acc[g], 0, 0, 0);
            }
            float4v cold = creg, cnew;
            float h2s[4];
#pragma unroll
            for (int r = 0; r < 4; ++r) {
                float c2 = sigm(acc[1][r] + bg[1]) * cold[r] + sigm(acc[0][r] + bg[0]) * tanh_(acc[2][r] + bg[2]);
                float h2 = sigm(acc[3][r] + bg[3]) * tanh_(c2);
                cnew[r] = c2;
                h2s[r] = h2;
                int row = wave * 16 + quad * 4 + r;
                sm.d.hpub[row][l15] = (_Float16)h2;
            }
            creg = cnew;
            __syncthreads();   // hpub complete
            // wide publish: one u64 per thread (128 rows x 16 f16 = 4 KB)
            {
                int prow = tid >> 2, jj = tid & 3;
                ull v = *((const ull*)&sm.d.hpub[prow][0] + jj);
                st_dev_u64((ull*)(hdB + (size_t)phdout * 524288 + (size_t)(r0 + prow) * 256
                           + (size_t)c * 32 + (size_t)jj * 8), v);
            }
            WAIT_VM0();
            __syncthreads();   // all publishes drained
            if (tid == 0) at_add_u32(dcp, 1u);
            // output heads (off the critical chain, after signal)
#pragma unroll
            for (int r = 0; r < 4; ++r) {
                int row = wave * 16 + quad * 4 + r;
                float pon = h2s[r] * won, pos = h2s[r] * wos;
#pragma unroll
                for (int off = 8; off; off >>= 1) {
                    pon += __shfl_down(pon, off, 16);
                    pos += __shfl_down(pos, off, 16);
                }
                if (l15 == 0) {
                    float* o = outs + ((size_t)t * ROWS + (r0 + row)) * 2;
                    at_add_f32(o, pon);
                    at_add_f32(o + 1, pos);
                }
            }
        }
    }
}

// Assemble data outputs for t in [20,126]; head biases added here.
__global__ __launch_bounds__(256) void assemble_kernel(
    const float* __restrict__ input, const float* __restrict__ ws, float* __restrict__ out,
    const float* __restrict__ onb, const float* __restrict__ osb)
{
    const float* outs = ws + OFF_OUTS;
    int idx = blockIdx.x * 256 + threadIdx.x;  // (b, tt, s)
    if (idx >= B_ * TOUT * S_) return;
    float b_on = onb[0], b_os = osb[0];
    int s = idx & 127;
    int tmp = idx >> 7;
    int tt = tmp % TOUT;
    int b = tmp / TOUT;
    int t = tt + TPRED;
    int row = b * S_ + s;
    float o0 = outs[((size_t)t * ROWS + row) * 2 + 0] + b_on;
    float o1 = outs[((size_t)t * ROWS + row) * 2 + 1] + b_os;
    float inflow = (s == 0) ? input[(((size_t)b * T_ + (t + 1)) * S_ + 0) * 4 + 1]
                            : (outs[((size_t)t * ROWS + row - 1) * 2 + 0] + b_on);
    float numc = input[(((size_t)b * T_ + t) * S_ + s) * 4 + 2] + inflow - o0;
    float spd = (s == 0) ? input[(((size_t)b * T_ + (t + 1)) * S_ + 0) * 4 + 3] : o1;
    float4 v = make_float4(o0, inflow, numc, spd);
    reinterpret_cast<float4*>(out)[idx] = v;
}

extern "C" void kernel_launch(void* const* d_in, const int* in_sizes, int n_in,
                              void* d_out, int out_size, void* d_ws, size_t ws_size,
                              hipStream_t stream) {
    const float* input = (const float*)d_in[0];
    const float* nWx = (const float*)d_in[1];
    const float* nWh = (const float*)d_in[2];
    const float* nWa = (const float*)d_in[3];
    const float* nWb = (const float*)d_in[4];
    const float* nb  = (const float*)d_in[5];
    const float* sWx = (const float*)d_in[6];
    const float* sWh = (const float*)d_in[7];
    const float* sWa = (const float*)d_in[8];
    const float* sWb = (const float*)d_in[9];
    const float* sb  = (const float*)d_in[10];
    const float* dWx = (const float*)d_in[11];
    const float* dWh = (const float*)d_in[12];
    const float* dWa = (const float*)d_in[13];
    const float* dWb = (const float*)d_in[14];
    const float* db  = (const float*)d_in[15];
    const float* onW = (const float*)d_in[16];
    const float* onb = (const float*)d_in[17];
    const float* osW = (const float*)d_in[18];
    const float* osb = (const float*)d_in[19];

    float* ws = (float*)d_ws;

    // zero h buffers (all parities), counters, outs accumulator
    hipMemsetAsync(ws, 0, (size_t)ZERO_DW * 4, stream);

    // pack weights into MFMA B-fragment tiles (once per call)
    pack_weights<<<dim3((PACK_DWORDS + 255) / 256), dim3(256), 0, stream>>>(
        nWx, nWh, nWa, nWb, nb, sWx, sWh, sWa, sWb, sb,
        dWx, dWh, dWa, dWb, (unsigned int*)ws);

    // cooperative launch (co-residency guarantee); sync via counters inside
    void* kargs[] = {
        (void*)&input, (void*)&db, (void*)&onW, (void*)&onb,
        (void*)&osW, (void*)&osb, (void*)&ws
    };
    hipLaunchCooperativeKernel((void*)pipe_persist, dim3(NBLK), dim3(TB),
                               kargs, 0, stream);

    int nout = B_ * TOUT * S_;
    assemble_kernel<<<dim3((nout + 255) / 256), dim3(256), 0, stream>>>(
        input, ws, (float*)d_out, onb, osb);
}